// Round 9
// baseline (976.018 us; speedup 1.0000x reference)
//
#include <hip/hip_runtime.h>

// Group_10: replicate-pad 3x3 conv (4,512,32,32)->(4,9728,32,32) + bias,
// then faithful-PS reinterpretation to (4,152,256,256).
//
// Round 9: R3 baseline (best: 481us gemm, MfmaUtil 34.6) + ONE change:
// non-temporal epilogue stores. Mechanism: output stream (~160MB) was
// evicting the packed A/B panels (128MB) from the 256MB L3, so K-loop
// staging paid HBM latency (~900cy) inside the barrier drain every K-step
// (FETCH 1.15GB per dispatch = ~9x operand re-fetch). nt stores keep
// operands L3-resident; drains become L3-class.
//
// Mapping (HW-verified R3): cc=co&63, n=co>>6, i=(cc>>1)*8+(w&7),
//   j=(cc&1)*128+(h>>1)*8+(h&1)*4+(w>>3)

#define CIN   512
#define COUT  9728
#define NBAT  4
#define KTOT  4608
#define KSTEPS 72           // K = 72 * 64
#define MB_TILES 32         // M = 4096 = 32*128
#define NB_TILES 76         // N = 9728 = 76*128
#define TILE_BYTES 16384    // 128 rows * 64 bf16 * 2B

typedef __bf16 bf16x8 __attribute__((ext_vector_type(8)));
typedef float  f32x4  __attribute__((ext_vector_type(4)));

// ---------------- fallback: direct conv (correct, slow) ----------------
__global__ __launch_bounds__(256) void conv_ps_direct(
    const float* __restrict__ x, const float* __restrict__ Wt,
    const float* __restrict__ bias, float* __restrict__ out)
{
    int flat = blockIdx.x * 256 + threadIdx.x;
    int w  = flat & 31;
    int h  = (flat >> 5) & 31;
    int t  = flat >> 10;
    int co = t % COUT;
    int b  = t / COUT;

    const float* xb = x + (size_t)b * CIN * 1024;
    const float* Wc = Wt + (size_t)co * CIN * 9;

    int hm = h > 0  ? h - 1 : 0;
    int hp = h < 31 ? h + 1 : 31;
    int wm = w > 0  ? w - 1 : 0;
    int wp = w < 31 ? w + 1 : 31;

    float acc = bias[co];
    #pragma unroll 4
    for (int ci = 0; ci < CIN; ++ci) {
        const float* xc = xb + ci * 1024;
        const float* wf = Wc + ci * 9;
        const float* r0 = xc + hm * 32;
        const float* r1 = xc + h  * 32;
        const float* r2 = xc + hp * 32;
        acc += wf[0] * r0[wm] + wf[1] * r0[w] + wf[2] * r0[wp];
        acc += wf[3] * r1[wm] + wf[4] * r1[w] + wf[5] * r1[wp];
        acc += wf[6] * r2[wm] + wf[7] * r2[w] + wf[8] * r2[wp];
    }
    int cc = co & 63;
    int n  = co >> 6;
    int i  = ((cc >> 1) << 3) | (w & 7);
    int j  = ((cc & 1) << 7) | ((h >> 1) << 3) | ((h & 1) << 2) | (w >> 3);
    out[(((size_t)b * 152 + n) * 256 + i) * 256 + j] = acc;
}

// ---------------- pack W: fp32 -> bf16, tiled + swizzled (R3) ----------------
// Granule index G = ((nb*72 + kt)*128 + r)*8 + s ; granule (r,s) holds
// logical K-granule g = s ^ (r&7) of row n = nb*128+r.
__global__ __launch_bounds__(256) void pack_W(const float* __restrict__ Wt,
                                              __bf16* __restrict__ Wws)
{
    int G = blockIdx.x * 256 + threadIdx.x;   // < 76*72*128*8 = 5,603,328
    int s    = G & 7;
    int r    = (G >> 3) & 127;
    int rest = G >> 10;                        // nb*72 + kt
    int kt = rest % KSTEPS;
    int nb = rest / KSTEPS;
    int n  = nb * 128 + r;
    int g  = s ^ (r & 7);
    int k0 = kt * 64 + g * 8;

    const float* src = Wt + (size_t)n * KTOT + k0;
    float4 v0 = *(const float4*)(src);
    float4 v1 = *(const float4*)(src + 4);
    bf16x8 o;
    o[0] = (__bf16)v0.x; o[1] = (__bf16)v0.y; o[2] = (__bf16)v0.z; o[3] = (__bf16)v0.w;
    o[4] = (__bf16)v1.x; o[5] = (__bf16)v1.y; o[6] = (__bf16)v1.z; o[7] = (__bf16)v1.w;
    *(bf16x8*)(Wws + (size_t)G * 8) = o;
}

// ---------------- pack A: im2col bf16, same tiling/swizzle (R3) ----------------
__global__ __launch_bounds__(256) void pack_A(const float* __restrict__ x,
                                              __bf16* __restrict__ Aws)
{
    int G = blockIdx.x * 256 + threadIdx.x;   // < 32*72*128*8 = 2,359,296
    int s    = G & 7;
    int r    = (G >> 3) & 127;
    int rest = G >> 10;                        // mb*72 + kt
    int kt = rest % KSTEPS;
    int mb = rest / KSTEPS;
    int m  = mb * 128 + r;
    int b  = m >> 10;
    int h  = (m >> 5) & 31;
    int w  = m & 31;
    int g  = s ^ (r & 7);
    int k0 = kt * 64 + g * 8;

    const float* xb = x + (size_t)b * CIN * 1024;
    bf16x8 o;
    #pragma unroll
    for (int e = 0; e < 8; ++e) {
        int k  = k0 + e;
        int ci = k / 9;
        int r9 = k - ci * 9;
        int kh = r9 / 3;
        int kw = r9 - kh * 3;
        int hh = h + kh - 1; hh = hh < 0 ? 0 : (hh > 31 ? 31 : hh);
        int ww = w + kw - 1; ww = ww < 0 ? 0 : (ww > 31 ? 31 : ww);
        o[e] = (__bf16)xb[(ci << 10) + (hh << 5) + ww];
    }
    *(bf16x8*)(Aws + (size_t)G * 8) = o;
}

// ---------------- GEMM + fused phase-shift epilogue (R3 + nt stores) --------
__global__ __launch_bounds__(256) void gemm_ps(
    const __bf16* __restrict__ Aws, const __bf16* __restrict__ Wws,
    const float* __restrict__ bias, float* __restrict__ out)
{
    __shared__ __align__(16) char smem[32768];   // As: [0,16K), Bs: [16K,32K)

    int bid = blockIdx.x;
    int nb  = bid % NB_TILES;
    int mb  = bid / NB_TILES;
    int t    = threadIdx.x;
    int lane = t & 63;
    int wid  = t >> 6;
    int wm = wid >> 1, wn = wid & 1;          // 2x2 waves, 64x64 each

    const char* Abase = (const char*)Aws + (size_t)mb * KSTEPS * TILE_BYTES;
    const char* Bbase = (const char*)Wws + (size_t)nb * KSTEPS * TILE_BYTES;

    f32x4 acc[4][4] = {};

    // ds_read addresses (swizzled): row*128 + ((gran ^ (lane&7))<<4)
    int rA = wm * 64 + (lane & 15);
    int rB = wn * 64 + (lane & 15);
    int gsel = lane >> 4;
    int x7   = lane & 7;
    int offA0 = rA * 128 + ((gsel ^ x7) << 4);
    int offA1 = rA * 128 + (((gsel + 4) ^ x7) << 4);
    int offB0 = 16384 + rB * 128 + ((gsel ^ x7) << 4);
    int offB1 = 16384 + rB * 128 + (((gsel + 4) ^ x7) << 4);

    for (int kt = 0; kt < KSTEPS; ++kt) {
        __syncthreads();                       // previous compute done
        const char* As = Abase + kt * TILE_BYTES;
        const char* Bs = Bbase + kt * TILE_BYTES;
        #pragma unroll
        for (int i = 0; i < 4; ++i) {
            int G16 = (i * 256 + t) * 16;
            __builtin_amdgcn_global_load_lds(
                (const __attribute__((address_space(1))) void*)(As + G16),
                (__attribute__((address_space(3))) void*)(smem + G16), 16, 0, 0);
            __builtin_amdgcn_global_load_lds(
                (const __attribute__((address_space(1))) void*)(Bs + G16),
                (__attribute__((address_space(3))) void*)(smem + 16384 + G16), 16, 0, 0);
        }
        __syncthreads();                       // drains vmcnt(0) before barrier

        #pragma unroll
        for (int kc = 0; kc < 2; ++kc) {
            bf16x8 af[4], bfr[4];
            #pragma unroll
            for (int mi = 0; mi < 4; ++mi)
                af[mi] = *(const bf16x8*)(smem + (kc ? offA1 : offA0) + mi * 2048);
            #pragma unroll
            for (int ni = 0; ni < 4; ++ni)
                bfr[ni] = *(const bf16x8*)(smem + (kc ? offB1 : offB0) + ni * 2048);
            #pragma unroll
            for (int mi = 0; mi < 4; ++mi)
                #pragma unroll
                for (int ni = 0; ni < 4; ++ni)
                    acc[mi][ni] = __builtin_amdgcn_mfma_f32_16x16x32_bf16(
                        af[mi], bfr[ni], acc[mi][ni], 0, 0, 0);
        }
    }

    // epilogue: bias + phase-shift scatter — NON-TEMPORAL stores (the one
    // change vs R3): output stream must not evict A/B panels from L3.
    int M0 = mb * 128 + wm * 64;
    int N0 = nb * 128 + wn * 64;
    int nlane = lane & 15;
    int mrow  = (lane >> 4) * 4;

    #pragma unroll
    for (int ni = 0; ni < 4; ++ni) {
        int n  = N0 + ni * 16 + nlane;
        float bv = bias[n];
        int cc  = n & 63;
        int nch = n >> 6;
        int i_hi = (cc >> 1) << 3;
        int j_hi = (cc & 1) << 7;
        #pragma unroll
        for (int mi = 0; mi < 4; ++mi) {
            #pragma unroll
            for (int r = 0; r < 4; ++r) {
                int m = M0 + mi * 16 + mrow + r;
                int b = m >> 10, h = (m >> 5) & 31, w = m & 31;
                int i = i_hi | (w & 7);
                int j = j_hi | ((h >> 1) << 3) | ((h & 1) << 2) | (w >> 3);
                __builtin_nontemporal_store(
                    acc[mi][ni][r] + bv,
                    out + ((size_t)b * 152 + nch) * 65536 + i * 256 + j);
            }
        }
    }
}

extern "C" void kernel_launch(void* const* d_in, const int* in_sizes, int n_in,
                              void* d_out, int out_size, void* d_ws, size_t ws_size,
                              hipStream_t stream) {
    const float* x    = (const float*)d_in[0];
    const float* Wt   = (const float*)d_in[1];
    const float* bias = (const float*)d_in[2];
    float* out        = (float*)d_out;

    const size_t needW = (size_t)NB_TILES * KSTEPS * TILE_BYTES;  // 89,653,248
    const size_t needA = (size_t)MB_TILES * KSTEPS * TILE_BYTES;  // 37,748,736

    if (ws_size >= needW + needA) {
        __bf16* Wws = (__bf16*)d_ws;
        __bf16* Aws = (__bf16*)((char*)d_ws + needW);
        pack_W<<<21888, 256, 0, stream>>>(Wt, Wws);
        pack_A<<<9216, 256, 0, stream>>>(x, Aws);
        gemm_ps<<<MB_TILES * NB_TILES, 256, 0, stream>>>(Aws, Wws, bias, out);
    } else {
        const int total = NBAT * COUT * 1024;
        conv_ps_direct<<<total / 256, 256, 0, stream>>>(x, Wt, bias, out);
    }
}

// Round 10
// 495.764 us; speedup vs baseline: 1.9687x; 1.9687x over previous
//
#include <hip/hip_runtime.h>

// Group_10: replicate-pad 3x3 conv (4,512,32,32)->(4,9728,32,32) + bias,
// then faithful-PS reinterpretation to (4,152,256,256).
//
// Round 10: attack the measured binder = LDS bandwidth. R3 ratio:
// 96KB LDS traffic vs 620 MFMA-cyc per block-K-step (ceiling ~55%).
// This round: 256x128 block, 4 waves of 128x64 (acc 8x4 -> AGPRs),
// single-buffer 48KB LDS, R3's verified packs/swizzle/epilogue unchanged.
// New ratio: 144KB vs 1240 cyc -> ceiling ~73% (1.33x better).
// Grid 1216 = 8*152, bijective XCD swizzle (152 consecutive per XCD ->
// A-panels L2-resident).

#define CIN   512
#define COUT  9728
#define NBAT  4
#define KTOT  4608
#define KSTEPS 72           // K = 72 * 64
#define TB     16384        // packed tile: 128 rows x 64 bf16 x 2B
#define PANEL  (KSTEPS * TB)

typedef __bf16 bf16x8 __attribute__((ext_vector_type(8)));
typedef float  f32x4  __attribute__((ext_vector_type(4)));

// ---------------- fallback: direct conv (correct, slow) ----------------
__global__ __launch_bounds__(256) void conv_ps_direct(
    const float* __restrict__ x, const float* __restrict__ Wt,
    const float* __restrict__ bias, float* __restrict__ out)
{
    int flat = blockIdx.x * 256 + threadIdx.x;
    int w  = flat & 31;
    int h  = (flat >> 5) & 31;
    int t  = flat >> 10;
    int co = t % COUT;
    int b  = t / COUT;

    const float* xb = x + (size_t)b * CIN * 1024;
    const float* Wc = Wt + (size_t)co * CIN * 9;

    int hm = h > 0  ? h - 1 : 0;
    int hp = h < 31 ? h + 1 : 31;
    int wm = w > 0  ? w - 1 : 0;
    int wp = w < 31 ? w + 1 : 31;

    float acc = bias[co];
    #pragma unroll 4
    for (int ci = 0; ci < CIN; ++ci) {
        const float* xc = xb + ci * 1024;
        const float* wf = Wc + ci * 9;
        const float* r0 = xc + hm * 32;
        const float* r1 = xc + h  * 32;
        const float* r2 = xc + hp * 32;
        acc += wf[0] * r0[wm] + wf[1] * r0[w] + wf[2] * r0[wp];
        acc += wf[3] * r1[wm] + wf[4] * r1[w] + wf[5] * r1[wp];
        acc += wf[6] * r2[wm] + wf[7] * r2[w] + wf[8] * r2[wp];
    }
    int cc = co & 63;
    int n  = co >> 6;
    int i  = ((cc >> 1) << 3) | (w & 7);
    int j  = ((cc & 1) << 7) | ((h >> 1) << 3) | ((h & 1) << 2) | (w >> 3);
    out[(((size_t)b * 152 + n) * 256 + i) * 256 + j] = acc;
}

// -------- pack W: fp32 -> bf16, tiled + XOR-swizzled (R3, verified) --------
// Granule (r,s) of tile (nb128,kt) holds logical K-granule g = s^(r&7).
__global__ __launch_bounds__(256) void pack_W(const float* __restrict__ Wt,
                                              __bf16* __restrict__ Wws)
{
    int G = blockIdx.x * 256 + threadIdx.x;   // < 76*72*128*8
    int s    = G & 7;
    int r    = (G >> 3) & 127;
    int rest = G >> 10;                        // nb*72 + kt
    int kt = rest % KSTEPS;
    int nb = rest / KSTEPS;
    int n  = nb * 128 + r;
    int g  = s ^ (r & 7);
    int k0 = kt * 64 + g * 8;

    const float* src = Wt + (size_t)n * KTOT + k0;
    float4 v0 = *(const float4*)(src);
    float4 v1 = *(const float4*)(src + 4);
    bf16x8 o;
    o[0] = (__bf16)v0.x; o[1] = (__bf16)v0.y; o[2] = (__bf16)v0.z; o[3] = (__bf16)v0.w;
    o[4] = (__bf16)v1.x; o[5] = (__bf16)v1.y; o[6] = (__bf16)v1.z; o[7] = (__bf16)v1.w;
    *(bf16x8*)(Wws + (size_t)G * 8) = o;
}

// -------- pack A: im2col bf16, same tiling/swizzle (R3, verified) --------
__global__ __launch_bounds__(256) void pack_A(const float* __restrict__ x,
                                              __bf16* __restrict__ Aws)
{
    int G = blockIdx.x * 256 + threadIdx.x;   // < 32*72*128*8
    int s    = G & 7;
    int r    = (G >> 3) & 127;
    int rest = G >> 10;                        // mb*72 + kt
    int kt = rest % KSTEPS;
    int mb = rest / KSTEPS;
    int m  = mb * 128 + r;
    int b  = m >> 10;
    int h  = (m >> 5) & 31;
    int w  = m & 31;
    int g  = s ^ (r & 7);
    int k0 = kt * 64 + g * 8;

    const float* xb = x + (size_t)b * CIN * 1024;
    bf16x8 o;
    #pragma unroll
    for (int e = 0; e < 8; ++e) {
        int k  = k0 + e;
        int ci = k / 9;
        int r9 = k - ci * 9;
        int kh = r9 / 3;
        int kw = r9 - kh * 3;
        int hh = h + kh - 1; hh = hh < 0 ? 0 : (hh > 31 ? 31 : hh);
        int ww = w + kw - 1; ww = ww < 0 ? 0 : (ww > 31 ? 31 : ww);
        o[e] = (__bf16)xb[(ci << 10) + (hh << 5) + ww];
    }
    *(bf16x8*)(Aws + (size_t)G * 8) = o;
}

// ---- 256x128 GEMM: 4 waves of 128x64, single-buffer LDS, fused PS ----
__global__ __launch_bounds__(256, 2) void gemm_ps(
    const __bf16* __restrict__ Aws, const __bf16* __restrict__ Wws,
    const float* __restrict__ bias, float* __restrict__ out)
{
    __shared__ __align__(16) char smem[49152];  // A0:[0,16K) A1:[16K,32K) B:[32K,48K)

    // XCD-bijective swizzle: 1216 blocks = 8 * 152
    int bid = blockIdx.x;
    int g   = (bid & 7) * 152 + (bid >> 3);
    int nb  = g % 76;
    int mb  = g / 76;          // 0..15

    int t    = threadIdx.x;
    int lane = t & 63;
    int wid  = t >> 6;
    int wm = wid >> 1, wn = wid & 1;       // 2x2 waves; wave tile 128x64

    const char* A0 = (const char*)Aws + (size_t)(mb * 2 + 0) * PANEL;
    const char* A1 = (const char*)Aws + (size_t)(mb * 2 + 1) * PANEL;
    const char* Bb = (const char*)Wws + (size_t)nb * PANEL;

    f32x4 acc[8][4] = {};

    int rb   = lane & 15;
    int gsel = lane >> 4;      // 0..3
    int x7   = lane & 7;
    int apanel = wm << 14;     // wm*16384
    int kxa[2], kxb[2];
    kxa[0] = ((gsel    ) ^ x7) << 4;
    kxa[1] = ((gsel + 4) ^ x7) << 4;
    kxb[0] = kxa[0]; kxb[1] = kxa[1];

    for (int kt = 0; kt < KSTEPS; ++kt) {
        __syncthreads();                       // previous compute done
        const char* As0 = A0 + (size_t)kt * TB;
        const char* As1 = A1 + (size_t)kt * TB;
        const char* Bs  = Bb + (size_t)kt * TB;
        #pragma unroll
        for (int i = 0; i < 4; ++i) {
            int G16 = (i * 256 + t) * 16;
            __builtin_amdgcn_global_load_lds(
                (const __attribute__((address_space(1))) void*)(As0 + G16),
                (__attribute__((address_space(3))) void*)(smem + G16), 16, 0, 0);
            __builtin_amdgcn_global_load_lds(
                (const __attribute__((address_space(1))) void*)(As1 + G16),
                (__attribute__((address_space(3))) void*)(smem + 16384 + G16), 16, 0, 0);
            __builtin_amdgcn_global_load_lds(
                (const __attribute__((address_space(1))) void*)(Bs + G16),
                (__attribute__((address_space(3))) void*)(smem + 32768 + G16), 16, 0, 0);
        }
        __syncthreads();                       // drains vmcnt(0) before barrier

        #pragma unroll
        for (int kc = 0; kc < 2; ++kc) {
            bf16x8 af[8], bfr[4];
            #pragma unroll
            for (int mi = 0; mi < 8; ++mi)
                af[mi] = *(const bf16x8*)(smem + apanel + (mi * 16 + rb) * 128 + kxa[kc]);
            #pragma unroll
            for (int ni = 0; ni < 4; ++ni)
                bfr[ni] = *(const bf16x8*)(smem + 32768 + ((wn * 64) + ni * 16 + rb) * 128 + kxb[kc]);
            #pragma unroll
            for (int mi = 0; mi < 8; ++mi)
                #pragma unroll
                for (int ni = 0; ni < 4; ++ni)
                    acc[mi][ni] = __builtin_amdgcn_mfma_f32_16x16x32_bf16(
                        af[mi], bfr[ni], acc[mi][ni], 0, 0, 0);
        }
    }

    // epilogue: bias + phase-shift scatter (R3-verified; WRITE ~ideal)
    int M0 = mb * 256 + wm * 128;
    int N0 = nb * 128 + wn * 64;
    int nlane = lane & 15;
    int mrow  = (lane >> 4) * 4;

    #pragma unroll
    for (int ni = 0; ni < 4; ++ni) {
        int n  = N0 + ni * 16 + nlane;
        float bv = bias[n];
        int cc  = n & 63;
        int nch = n >> 6;
        int i_hi = (cc >> 1) << 3;
        int j_hi = (cc & 1) << 7;
        #pragma unroll
        for (int mi = 0; mi < 8; ++mi) {
            #pragma unroll
            for (int r = 0; r < 4; ++r) {
                int m = M0 + mi * 16 + mrow + r;
                int b = m >> 10, h = (m >> 5) & 31, w = m & 31;
                int i = i_hi | (w & 7);
                int j = j_hi | ((h >> 1) << 3) | ((h & 1) << 2) | (w >> 3);
                out[((size_t)b * 152 + nch) * 65536 + i * 256 + j] =
                    acc[mi][ni][r] + bv;
            }
        }
    }
}

extern "C" void kernel_launch(void* const* d_in, const int* in_sizes, int n_in,
                              void* d_out, int out_size, void* d_ws, size_t ws_size,
                              hipStream_t stream) {
    const float* x    = (const float*)d_in[0];
    const float* Wt   = (const float*)d_in[1];
    const float* bias = (const float*)d_in[2];
    float* out        = (float*)d_out;

    const size_t needW = (size_t)76 * PANEL;  // 89,653,248
    const size_t needA = (size_t)32 * PANEL;  // 37,748,736

    if (ws_size >= needW + needA) {
        __bf16* Wws = (__bf16*)d_ws;
        __bf16* Aws = (__bf16*)((char*)d_ws + needW);
        pack_W<<<21888, 256, 0, stream>>>(Wt, Wws);
        pack_A<<<9216, 256, 0, stream>>>(x, Aws);
        gemm_ps<<<16 * 76, 256, 0, stream>>>(Aws, Wws, bias, out);
    } else {
        const int total = NBAT * COUT * 1024;
        conv_ps_direct<<<total / 256, 256, 0, stream>>>(x, Wt, bias, out);
    }
}